// Round 8
// baseline (300.076 us; speedup 1.0000x reference)
//
#include <hip/hip_runtime.h>
#include <hip/hip_fp16.h>
#include <math.h>

#define N_NODES 100000
#define N_EDGES 1600000
#define N_GRAPHS 64
#define EMB 128
#define HID 64

#define BUCKET_BITS 9
#define BUCKET_SZ   512
#define NB          196   // ceil(N_NODES / 512)
#define EPB         4096  // edges per block in bucket passes
#define P12_BLOCKS  391   // ceil(N_EDGES / 4096)
#define NPB         16    // nodes per gin block

// ---------------- fp16 packed helpers ----------------

typedef _Float16 half2_t __attribute__((ext_vector_type(2)));

__device__ inline unsigned hadd2u(unsigned a, unsigned b) {
    __half2 ha = __builtin_bit_cast(__half2, a);
    __half2 hb = __builtin_bit_cast(__half2, b);
    return __builtin_bit_cast(unsigned, __hadd2(ha, hb));
}

// relu on two packed halves, branchless (sign-mask); -0 -> +0
__device__ inline unsigned relu2(unsigned v) {
    unsigned m = (v >> 15) & 0x00010001u;
    return v & ~(m * 0xFFFFu);
}

__device__ inline float fdot2h(unsigned a, unsigned b, float c) {
#if __has_builtin(__builtin_amdgcn_fdot2)
    half2_t ha = __builtin_bit_cast(half2_t, a);
    half2_t hb = __builtin_bit_cast(half2_t, b);
    return __builtin_amdgcn_fdot2(ha, hb, c, false);
#else
    __half2 ha = __builtin_bit_cast(__half2, a);
    __half2 hb = __builtin_bit_cast(__half2, b);
    float2 fa = __half22float2(ha);
    float2 fb = __half22float2(hb);
    return fmaf(fa.x, fb.x, fmaf(fa.y, fb.y, c));
#endif
}

__device__ inline unsigned pack2(float a, float b) {
    __half2 p = __floats2half2_rn(a, b);
    return __builtin_bit_cast(unsigned, p);
}

// ---------------- block-wide exclusive scan over 256 threads ----------------

__device__ inline int block_scan_excl_256(int v) {
    int t = threadIdx.x;
    int lane = t & 63, wid = t >> 6;
    int incl = v;
    #pragma unroll
    for (int off = 1; off < 64; off <<= 1) {
        int u = __shfl_up(incl, off);
        if (lane >= off) incl += u;
    }
    __shared__ int wsum[4];
    if (lane == 63) wsum[wid] = incl;
    __syncthreads();
    int woff = 0;
    for (int w = 0; w < wid; ++w) woff += wsum[w];
    __syncthreads();
    return woff + incl - v;
}

// ---------------- CSR build via bucket semi-sort ----------------

__global__ __launch_bounds__(256) void bucket_count(const int* __restrict__ dst,
                                                    int* __restrict__ bucketCnt, int e) {
    __shared__ int bins[NB];
    for (int i = threadIdx.x; i < NB; i += 256) bins[i] = 0;
    __syncthreads();
    int base = blockIdx.x * EPB;
    #pragma unroll
    for (int j = 0; j < 16; ++j) {
        int i = base + j * 256 + threadIdx.x;
        if (i < e) atomicAdd(&bins[dst[i] >> BUCKET_BITS], 1);
    }
    __syncthreads();
    for (int i = threadIdx.x; i < NB; i += 256)
        if (bins[i]) atomicAdd(&bucketCnt[i], bins[i]);
}

__global__ void bucket_scan(const int* __restrict__ bucketCnt, int* __restrict__ bucketOff,
                            int* __restrict__ bucketCur, int* __restrict__ row_ptr) {
    int t = threadIdx.x;
    int v = (t < NB) ? bucketCnt[t] : 0;
    int excl = block_scan_excl_256(v);
    if (t < NB) { bucketOff[t] = excl; bucketCur[t] = excl; }
    if (t == 0) { bucketOff[NB] = N_EDGES; row_ptr[N_NODES] = N_EDGES; }
}

__global__ __launch_bounds__(256) void bucket_scatter(const int* __restrict__ src,
                                                      const int* __restrict__ dst,
                                                      int* __restrict__ bucketCur,
                                                      uint2* __restrict__ sorted, int e) {
    __shared__ int bins[NB];
    __shared__ int lbase[NB];
    __shared__ int gbase[NB];
    __shared__ int cur[NB];
    __shared__ uint2 stage[EPB];   // 32 KB

    for (int i = threadIdx.x; i < NB; i += 256) bins[i] = 0;
    __syncthreads();

    int base = blockIdx.x * EPB;
    #pragma unroll
    for (int j = 0; j < 16; ++j) {
        int i = base + j * 256 + threadIdx.x;
        if (i < e) atomicAdd(&bins[dst[i] >> BUCKET_BITS], 1);
    }
    __syncthreads();

    int t = threadIdx.x;
    int v = (t < NB) ? bins[t] : 0;
    int excl = block_scan_excl_256(v);
    if (t < NB) {
        lbase[t] = excl;
        cur[t]   = excl;
        gbase[t] = v ? atomicAdd(&bucketCur[t], v) : 0;
    }
    __syncthreads();

    #pragma unroll
    for (int j = 0; j < 16; ++j) {
        int i = base + j * 256 + threadIdx.x;
        if (i < e) {
            int d = dst[i], s = src[i];
            int p = atomicAdd(&cur[d >> BUCKET_BITS], 1);
            stage[p] = make_uint2((unsigned)d, (unsigned)s);
        }
    }
    __syncthreads();

    int cnt = min(EPB, e - base);
    for (int idx = threadIdx.x; idx < cnt; idx += 256) {
        uint2 ed = stage[idx];
        int b = (int)(ed.x >> BUCKET_BITS);
        sorted[gbase[b] + (idx - lbase[b])] = ed;   // contiguous runs per bucket
    }
}

__global__ __launch_bounds__(256) void bucket_csr(const uint2* __restrict__ sorted,
                                                  const int* __restrict__ bucketOff,
                                                  int* __restrict__ row_ptr,
                                                  int* __restrict__ col_idx) {
    int b  = blockIdx.x;
    int S  = bucketOff[b];
    int Eb = bucketOff[b + 1];
    int n0 = b << BUCKET_BITS;
    int nNodes = min(BUCKET_SZ, N_NODES - n0);

    __shared__ int cnt[BUCKET_SZ];
    __shared__ int excl[BUCKET_SZ];
    __shared__ int cur[BUCKET_SZ];

    for (int i = threadIdx.x; i < BUCKET_SZ; i += 256) cnt[i] = 0;
    __syncthreads();

    for (int idx = S + threadIdx.x; idx < Eb; idx += 256)
        atomicAdd(&cnt[(int)sorted[idx].x - n0], 1);
    __syncthreads();

    int t = threadIdx.x;
    int v = cnt[2 * t] + cnt[2 * t + 1];
    int pe = block_scan_excl_256(v);
    excl[2 * t]     = pe;
    excl[2 * t + 1] = pe + cnt[2 * t];
    __syncthreads();

    for (int i = threadIdx.x; i < nNodes; i += 256)
        row_ptr[n0 + i] = S + excl[i];
    for (int i = threadIdx.x; i < BUCKET_SZ; i += 256) cur[i] = excl[i];
    __syncthreads();

    for (int idx = S + threadIdx.x; idx < Eb; idx += 256) {
        uint2 ed = sorted[idx];
        int ln = (int)ed.x - n0;
        int slot = S + atomicAdd(&cur[ln], 1);
        col_idx[slot] = (int)ed.y;
    }
}

// ---------------- weight pre-pack: 5 matrices 64x64 fp32 -> packed fp16 [k2][o] ----------------

__global__ void wpack5(const float* __restrict__ w0, const float* __restrict__ w1,
                       const float* __restrict__ w2, const float* __restrict__ w3,
                       const float* __restrict__ w4, unsigned* __restrict__ out) {
    int m = blockIdx.x >> 3;                       // 8 blocks per matrix
    int i = (blockIdx.x & 7) * 256 + threadIdx.x;  // 0..2047
    const float* W = (m == 0) ? w0 : (m == 1) ? w1 : (m == 2) ? w2 : (m == 3) ? w3 : w4;
    int k2 = i >> 6, o = i & 63;
    out[m * 2048 + i] = pack2(W[(2 * k2) * 64 + o], W[(2 * k2 + 1) * 64 + o]);
}

// ---------------- dense projection (layer 1 only): y = x @ W (128 -> 64), fp16 out ----------------

template <int DIN>
__global__ __launch_bounds__(256) void project_kernel(const float* __restrict__ h,
                                                      const float* __restrict__ W,
                                                      ushort* __restrict__ y) {
    int wid  = threadIdx.x >> 6;
    int lane = threadIdx.x & 63;
    int node = blockIdx.x * 64 + lane;
    bool valid = node < N_NODES;
    const float4* row = reinterpret_cast<const float4*>(h + (size_t)(valid ? node : 0) * DIN);
    int ob = __builtin_amdgcn_readfirstlane(wid * 16);

    float acc[16];
    #pragma unroll
    for (int o = 0; o < 16; ++o) acc[o] = 0.0f;

    #pragma unroll 4
    for (int k4 = 0; k4 < DIN / 4; ++k4) {
        float4 a = row[k4];
        #pragma unroll
        for (int kk = 0; kk < 4; ++kk) {
            int k = k4 * 4 + kk;
            float av = (kk == 0) ? a.x : (kk == 1) ? a.y : (kk == 2) ? a.z : a.w;
            const float* wr = W + k * 64 + ob;   // uniform address -> s_load
            #pragma unroll
            for (int o = 0; o < 16; ++o)
                acc[o] = fmaf(av, wr[o], acc[o]);
        }
    }

    if (valid) {
        uint4 p0, p1;
        p0.x = pack2(acc[0], acc[1]);   p0.y = pack2(acc[2], acc[3]);
        p0.z = pack2(acc[4], acc[5]);   p0.w = pack2(acc[6], acc[7]);
        p1.x = pack2(acc[8], acc[9]);   p1.y = pack2(acc[10], acc[11]);
        p1.z = pack2(acc[12], acc[13]); p1.w = pack2(acc[14], acc[15]);
        uint4* yr = reinterpret_cast<uint4*>(y + (size_t)node * 64 + ob);
        yr[0] = p0;
        yr[1] = p1;
    }
}

// ---------------- fused GIN layer ----------------
// lane = (e8 = lane>>3, c8 = lane&7): 8 lanes x uint4(16B) = one 128B fp16 row.
// Per node: 4 predicated uint4 loads cover deg<=32; edge ids preloaded to LDS
// (ranges of the wave's 4 consecutive nodes are contiguous in CSR).
// Software pipeline: node t+1's row loads are issued before node t's compute.
// MODE 0: ... -> h = relu(MLP) -> fused y_next = h @ W1next (writes y_next fp16).
// MODE 1: writes h = MLP out (no relu) as fp16 for pooling.

__device__ __forceinline__ void prefetch_node(const uint4* __restrict__ yp4,
                                              const int* civ, int s0,
                                              int start, int end, int e8, int c8, int node,
                                              uint4& u0, uint4& u1, uint4& u2, uint4& u3,
                                              uint4& us) {
    uint4 z = make_uint4(0u, 0u, 0u, 0u);
    u0 = z; u1 = z; u2 = z; u3 = z; us = z;
    if (e8 == 0) us = yp4[(size_t)node * 8 + c8];      // self row
    int pf_end = min(min(end, start + 32), s0 + 128);
    int d = start - s0;
    int p = start + e8;
    if (p < pf_end)      u0 = yp4[(size_t)civ[d + e8] * 8 + c8];
    if (p + 8 < pf_end)  u1 = yp4[(size_t)civ[d + 8 + e8] * 8 + c8];
    if (p + 16 < pf_end) u2 = yp4[(size_t)civ[d + 16 + e8] * 8 + c8];
    if (p + 24 < pf_end) u3 = yp4[(size_t)civ[d + 24 + e8] * 8 + c8];
}

template <int MODE>
__global__ __launch_bounds__(256) void gin_fused(const ushort* __restrict__ y,
                                                 const int* __restrict__ row_ptr,
                                                 const int* __restrict__ col_idx,
                                                 const float* __restrict__ b1,
                                                 const unsigned* __restrict__ W2p,
                                                 const float* __restrict__ b2,
                                                 const unsigned* __restrict__ W1p,
                                                 ushort* __restrict__ out) {
    __shared__ unsigned sW2p[32 * 64];
    __shared__ unsigned sW1p[MODE == 0 ? 32 * 64 : 64];
    __shared__ unsigned stp[4][32];
    __shared__ ushort   sh[4][64];
    __shared__ int      sciv[4][128];

    {
        const uint4* a = reinterpret_cast<const uint4*>(W2p);
        uint4* d = reinterpret_cast<uint4*>(sW2p);
        d[threadIdx.x]       = a[threadIdx.x];
        d[threadIdx.x + 256] = a[threadIdx.x + 256];
        if (MODE == 0) {
            const uint4* a1 = reinterpret_cast<const uint4*>(W1p);
            uint4* d1 = reinterpret_cast<uint4*>(sW1p);
            d1[threadIdx.x]       = a1[threadIdx.x];
            d1[threadIdx.x + 256] = a1[threadIdx.x + 256];
        }
    }
    __syncthreads();

    int wid = threadIdx.x >> 6, lane = threadIdx.x & 63;
    int e8 = lane >> 3, c8 = lane & 7;
    int nb4 = blockIdx.x * NPB + wid * 4;

    const uint4* yp4 = reinterpret_cast<const uint4*>(y);
    int* civ = sciv[wid];

    int rpl = row_ptr[nb4 + min(lane, 4)];
    int s0  = __shfl(rpl, 0);
    int eAll = __shfl(rpl, 4);

    {   // preload up to 128 edge ids (wave's 4 nodes are contiguous in CSR)
        int i1 = s0 + lane, i2 = s0 + 64 + lane;
        civ[lane]      = (i1 < eAll) ? col_idx[i1] : 0;
        civ[64 + lane] = (i2 < eAll) ? col_idx[i2] : 0;
    }

    // b1 packs for this lane's 8 channels (chunk c8)
    float4 ba = reinterpret_cast<const float4*>(b1)[2 * c8];
    float4 bb = reinterpret_cast<const float4*>(b1)[2 * c8 + 1];
    unsigned bp0 = pack2(ba.x, ba.y), bp1 = pack2(ba.z, ba.w);
    unsigned bp2 = pack2(bb.x, bb.y), bp3 = pack2(bb.z, bb.w);
    float b2v = b2[lane];

    uint4 A0, A1, A2, A3, AS, B0, B1, B2, B3, BS;
    prefetch_node(yp4, civ, s0, __shfl(rpl, 0), __shfl(rpl, 1), e8, c8, nb4,
                  A0, A1, A2, A3, AS);

#define GIN_ITER(T, C0, C1, C2, C3, CS, N0, N1, N2, N3, NS)                        \
    {                                                                              \
        int start = __shfl(rpl, T), end = __shfl(rpl, (T) + 1);                    \
        int node = nb4 + (T);                                                      \
        if ((T) < 3)                                                               \
            prefetch_node(yp4, civ, s0, end, __shfl(rpl, (T) + 2), e8, c8,         \
                          node + 1, N0, N1, N2, N3, NS);                           \
        unsigned a0 = CS.x, a1 = CS.y, a2 = CS.z, a3 = CS.w;                       \
        a0 = hadd2u(a0, C0.x); a1 = hadd2u(a1, C0.y);                              \
        a2 = hadd2u(a2, C0.z); a3 = hadd2u(a3, C0.w);                              \
        a0 = hadd2u(a0, C1.x); a1 = hadd2u(a1, C1.y);                              \
        a2 = hadd2u(a2, C1.z); a3 = hadd2u(a3, C1.w);                              \
        a0 = hadd2u(a0, C2.x); a1 = hadd2u(a1, C2.y);                              \
        a2 = hadd2u(a2, C2.z); a3 = hadd2u(a3, C2.w);                              \
        a0 = hadd2u(a0, C3.x); a1 = hadd2u(a1, C3.y);                              \
        a2 = hadd2u(a2, C3.z); a3 = hadd2u(a3, C3.w);                              \
        int pf_end = min(min(end, start + 32), max(s0 + 128, start));              \
        for (int base = pf_end; base < end; base += 8) { /* rare: deg>32 */        \
            uint4 v = make_uint4(0u, 0u, 0u, 0u);                                  \
            int p = base + e8;                                                     \
            if (p < end) v = yp4[(size_t)col_idx[p] * 8 + c8];                     \
            a0 = hadd2u(a0, v.x); a1 = hadd2u(a1, v.y);                            \
            a2 = hadd2u(a2, v.z); a3 = hadd2u(a3, v.w);                            \
        }                                                                          \
        a0 = hadd2u(a0, (unsigned)__shfl_xor((int)a0, 8));                         \
        a1 = hadd2u(a1, (unsigned)__shfl_xor((int)a1, 8));                         \
        a2 = hadd2u(a2, (unsigned)__shfl_xor((int)a2, 8));                         \
        a3 = hadd2u(a3, (unsigned)__shfl_xor((int)a3, 8));                         \
        a0 = hadd2u(a0, (unsigned)__shfl_xor((int)a0, 16));                        \
        a1 = hadd2u(a1, (unsigned)__shfl_xor((int)a1, 16));                        \
        a2 = hadd2u(a2, (unsigned)__shfl_xor((int)a2, 16));                        \
        a3 = hadd2u(a3, (unsigned)__shfl_xor((int)a3, 16));                        \
        a0 = hadd2u(a0, (unsigned)__shfl_xor((int)a0, 32));                        \
        a1 = hadd2u(a1, (unsigned)__shfl_xor((int)a1, 32));                        \
        a2 = hadd2u(a2, (unsigned)__shfl_xor((int)a2, 32));                        \
        a3 = hadd2u(a3, (unsigned)__shfl_xor((int)a3, 32));                        \
        a0 = relu2(hadd2u(a0, bp0)); a1 = relu2(hadd2u(a1, bp1));                  \
        a2 = relu2(hadd2u(a2, bp2)); a3 = relu2(hadd2u(a3, bp3));                  \
        if (e8 == 0)                                                               \
            reinterpret_cast<uint4*>(stp[wid])[c8] = make_uint4(a0, a1, a2, a3);   \
        float uacc = b2v;                                                          \
        const uint4* sp = reinterpret_cast<const uint4*>(stp[wid]);                \
        _Pragma("unroll")                                                          \
        for (int j = 0; j < 8; ++j) {                                              \
            uint4 q = sp[j];                                                       \
            uacc = fdot2h(q.x, sW2p[(4 * j + 0) * 64 + lane], uacc);               \
            uacc = fdot2h(q.y, sW2p[(4 * j + 1) * 64 + lane], uacc);               \
            uacc = fdot2h(q.z, sW2p[(4 * j + 2) * 64 + lane], uacc);               \
            uacc = fdot2h(q.w, sW2p[(4 * j + 3) * 64 + lane], uacc);               \
        }                                                                          \
        if (MODE == 0) {                                                           \
            float hl = fmaxf(uacc, 0.0f);                                          \
            sh[wid][lane] = __half_as_ushort(__float2half_rn(hl));                 \
            const uint4* shp = reinterpret_cast<const uint4*>(sh[wid]);            \
            float yv = 0.0f;                                                       \
            _Pragma("unroll")                                                      \
            for (int j = 0; j < 8; ++j) {                                          \
                uint4 q = shp[j];                                                  \
                yv = fdot2h(q.x, sW1p[(4 * j + 0) * 64 + lane], yv);               \
                yv = fdot2h(q.y, sW1p[(4 * j + 1) * 64 + lane], yv);               \
                yv = fdot2h(q.z, sW1p[(4 * j + 2) * 64 + lane], yv);               \
                yv = fdot2h(q.w, sW1p[(4 * j + 3) * 64 + lane], yv);               \
            }                                                                      \
            out[(size_t)node * 64 + lane] = __half_as_ushort(__float2half_rn(yv)); \
        } else {                                                                   \
            out[(size_t)node * 64 + lane] =                                        \
                __half_as_ushort(__float2half_rn(uacc));                           \
        }                                                                          \
    }

    GIN_ITER(0, A0, A1, A2, A3, AS, B0, B1, B2, B3, BS)
    GIN_ITER(1, B0, B1, B2, B3, BS, A0, A1, A2, A3, AS)
    GIN_ITER(2, A0, A1, A2, A3, AS, B0, B1, B2, B3, BS)
    GIN_ITER(3, B0, B1, B2, B3, BS, A0, A1, A2, A3, AS)
#undef GIN_ITER
}

// ---------------- pooling: segment mean over fp16 h (batch is sorted) ----------------

__global__ __launch_bounds__(256) void pool_kernel(const ushort* __restrict__ h,
                                                   const int* __restrict__ batch,
                                                   float* __restrict__ pool,
                                                   float* __restrict__ counts, int n) {
    int gwave = (blockIdx.x * 256 + threadIdx.x) >> 6;
    int lane  = threadIdx.x & 63;
    int s = gwave * 64;
    if (s >= n) return;
    int nhere = min(64, n - s);

    int bv = (s + lane < n) ? batch[s + lane] : -1;
    int cur = __shfl(bv, 0);
    float acc = 0.0f, cnt = 0.0f;

    #pragma unroll 1
    for (int i0 = 0; i0 < 64; i0 += 8) {
        float v[8];
        #pragma unroll
        for (int j = 0; j < 8; ++j) {
            int i = i0 + j;
            v[j] = (i < nhere)
                 ? __half2float(__ushort_as_half(h[(size_t)(s + i) * 64 + lane]))
                 : 0.0f;
        }
        #pragma unroll
        for (int j = 0; j < 8; ++j) {
            int i = i0 + j;
            if (i < nhere) {
                int g = __shfl(bv, i);
                if (g != cur) {   // wave-uniform, rare
                    atomicAdd(&pool[cur * 64 + lane], acc);
                    if (lane == 0) atomicAdd(&counts[cur], cnt);
                    cur = g; acc = 0.0f; cnt = 0.0f;
                }
                acc += v[j];
                cnt += 1.0f;
            }
        }
    }
    atomicAdd(&pool[cur * 64 + lane], acc);
    if (lane == 0) atomicAdd(&counts[cur], cnt);
}

// ---------------- head: pooled @ fc1 + b, @ pred + b, sigmoid ----------------

__global__ void head_kernel(const float* __restrict__ pool, const float* __restrict__ counts,
                            const float* __restrict__ fc1_W, const float* __restrict__ fc1_b,
                            const float* __restrict__ pred_W, const float* __restrict__ pred_b,
                            float* __restrict__ out) {
    int g = blockIdx.x;
    int t = threadIdx.x;
    float s = 0.0f;
    if (t < 32) {
        float cnt = fmaxf(counts[g], 1.0f);
        float inv = 1.0f / cnt;
        float f = fc1_b[t];
        #pragma unroll
        for (int k = 0; k < 64; ++k)
            f = fmaf(pool[g * 64 + k] * inv, fc1_W[k * 32 + t], f);
        s = f * pred_W[t];
    }
    #pragma unroll
    for (int off = 32; off > 0; off >>= 1) s += __shfl_down(s, off);
    if (t == 0) out[g] = 1.0f / (1.0f + expf(-(s + pred_b[0])));
}

// ---------------- launch ----------------

extern "C" void kernel_launch(void* const* d_in, const int* in_sizes, int n_in,
                              void* d_out, int out_size, void* d_ws, size_t ws_size,
                              hipStream_t stream) {
    const float* x      = (const float*)d_in[0];
    const int*   e_src  = (const int*)d_in[1];
    const int*   e_dst  = ((const int*)d_in[1]) + N_EDGES;
    const int*   batch  = (const int*)d_in[2];
    const float* c1_W1 = (const float*)d_in[3];
    const float* c1_b1 = (const float*)d_in[4];
    const float* c1_W2 = (const float*)d_in[5];
    const float* c1_b2 = (const float*)d_in[6];
    const float* c2_W1 = (const float*)d_in[7];
    const float* c2_b1 = (const float*)d_in[8];
    const float* c2_W2 = (const float*)d_in[9];
    const float* c2_b2 = (const float*)d_in[10];
    const float* c3_W1 = (const float*)d_in[11];
    const float* c3_b1 = (const float*)d_in[12];
    const float* c3_W2 = (const float*)d_in[13];
    const float* c3_b2 = (const float*)d_in[14];
    const float* fc1_W = (const float*)d_in[15];
    const float* fc1_b = (const float*)d_in[16];
    const float* predW = (const float*)d_in[17];
    const float* predb = (const float*)d_in[18];
    float* out = (float*)d_out;

    char* ws = (char*)d_ws;
    size_t off = 0;
    auto carve = [&](size_t bytes) {
        char* p = ws + off;
        off += (bytes + 255) & ~(size_t)255;
        return p;
    };
    ushort* y_a     = (ushort*)carve((size_t)N_NODES * 64 * 2);   // 12.8 MB
    ushort* y_b     = (ushort*)carve((size_t)N_NODES * 64 * 2);   // 12.8 MB
    ushort* hbuf    = (ushort*)carve((size_t)N_NODES * 64 * 2);   // 12.8 MB
    int*   row_ptr  = (int*)carve(((size_t)N_NODES + 1) * 4);
    int*   col_idx  = (int*)carve((size_t)N_EDGES * 4);
    int*   bucketCnt = (int*)carve(NB * 4);
    int*   bucketOff = (int*)carve((NB + 1) * 4);
    int*   bucketCur = (int*)carve(NB * 4);
    float* pool     = (float*)carve(N_GRAPHS * 64 * 4);
    float* counts   = (float*)carve(N_GRAPHS * 4);
    unsigned* Wp    = (unsigned*)carve(5 * 2048 * 4);             // packed fp16 weights
    // sorted edge array (12.8MB) aliases y_a: dead before proj1 writes y_a
    uint2* sorted = (uint2*)y_a;
    (void)ws_size; (void)n_in; (void)in_sizes; (void)out_size;

    const int GIN_BLOCKS  = N_NODES / NPB;             // 6250
    const int PROJ_BLOCKS = (N_NODES + 63) / 64;       // 1563
    const int POOL_BLOCKS = (N_NODES + 255) / 256;     // 391

    hipMemsetAsync(bucketCnt, 0, NB * 4, stream);
    hipMemsetAsync(pool, 0, (N_GRAPHS * 64 + N_GRAPHS) * 4 + 256, stream);

    // pack W2s (m=0,1,2) and next-layer W1s (m=3: c2_W1, m=4: c3_W1)
    wpack5<<<40, 256, 0, stream>>>(c1_W2, c2_W2, c3_W2, c2_W1, c3_W1, Wp);

    // CSR build via bucket semi-sort
    bucket_count<<<P12_BLOCKS, 256, 0, stream>>>(e_dst, bucketCnt, N_EDGES);
    bucket_scan<<<1, 256, 0, stream>>>(bucketCnt, bucketOff, bucketCur, row_ptr);
    bucket_scatter<<<P12_BLOCKS, 256, 0, stream>>>(e_src, e_dst, bucketCur, sorted, N_EDGES);
    bucket_csr<<<NB, 256, 0, stream>>>(sorted, bucketOff, row_ptr, col_idx);

    // layer 1 input projection (x fp32 -> y_a fp16)
    project_kernel<EMB><<<PROJ_BLOCKS, 256, 0, stream>>>(x, c1_W1, y_a);

    // fused layers
    gin_fused<0><<<GIN_BLOCKS, 256, 0, stream>>>(y_a, row_ptr, col_idx, c1_b1,
                                                 Wp + 0 * 2048, c1_b2, Wp + 3 * 2048, y_b);
    gin_fused<0><<<GIN_BLOCKS, 256, 0, stream>>>(y_b, row_ptr, col_idx, c2_b1,
                                                 Wp + 1 * 2048, c2_b2, Wp + 4 * 2048, y_a);
    gin_fused<1><<<GIN_BLOCKS, 256, 0, stream>>>(y_a, row_ptr, col_idx, c3_b1,
                                                 Wp + 2 * 2048, c3_b2, nullptr, hbuf);

    // pool + head
    pool_kernel<<<POOL_BLOCKS, 256, 0, stream>>>(hbuf, batch, pool, counts, N_NODES);
    head_kernel<<<N_GRAPHS, 64, 0, stream>>>(pool, counts, fc1_W, fc1_b, predW, predb, out);
}